// Round 9
// baseline (162.006 us; speedup 1.0000x reference)
//
#include <hip/hip_runtime.h>

#define N_USER 100000
#define N_ITEM 50000
#define NTOT   150000
#define D      64
#define NNZ    4000000
#define NQ     (NNZ / 4)
#define B      2048
#define NEG    8192
#define NSLOT  (B + B + NEG)        /* 12288 output rows */
#define CAP    128                  /* deg ~ Poisson(26.7); P(>=128) < 1e-40 */
#define NBW    ((NTOT + 31) / 32)   /* 4688 bitmap words (18.75 KB) */

typedef int   vint4   __attribute__((ext_vector_type(4)));
typedef float vfloat4 __attribute__((ext_vector_type(4)));

__device__ __forceinline__ int slot_row(int slot,
                                        const int* __restrict__ users,
                                        const int* __restrict__ pos,
                                        const int* __restrict__ neg) {
    if (slot < B)     return users[slot];
    if (slot < 2 * B) return N_USER + pos[slot - B];
    return N_USER + neg[slot - 2 * B];
}

__device__ __forceinline__ const float* e0_row(int c,
                                               const float* __restrict__ ue,
                                               const float* __restrict__ ie) {
    return (c < N_USER) ? &ue[(size_t)c * D] : &ie[(size_t)(c - N_USER) * D];
}

// ---------------------------------------------------------------------------
// Kernel 1: cntR[r] = 0 for every needed row. Plain stores — duplicates all
// write the same value; buckets are row-indexed so no owner/claim is needed.
// ---------------------------------------------------------------------------
__global__ void k_mark(const int* __restrict__ users,
                       const int* __restrict__ pos,
                       const int* __restrict__ neg,
                       int* __restrict__ cntR) {
    int slot = blockIdx.x * blockDim.x + threadIdx.x;
    if (slot >= NSLOT) return;
    cntR[slot_row(slot, users, pos, neg)] = 0;
}

// ---------------------------------------------------------------------------
// Kernel 2: stream all edges (non-temporal dwordx4, 2-deep pipelined).
// Each block builds its own LDS "row needed" bitmap from users/pos/neg
// (49 KB of L2-resident index reads + 12 LDS atomicOr per thread) — no
// global bitmap array, no clear kernel. Hit path: 4 B cnt atomic + packed
// 8 B NT store. Overflow (P<1e-40) drops; k_fin rescans exactly.
// 512 blocks x 1024 thr = 32 waves/CU.
// ---------------------------------------------------------------------------
__global__ __launch_bounds__(1024)
void k_scan(const int*   __restrict__ users,
            const int*   __restrict__ pos,
            const int*   __restrict__ neg,
            const int*   __restrict__ adj_row,
            const int*   __restrict__ adj_col,
            const float* __restrict__ adj_val,
            int*       __restrict__ cntR,
            long long* __restrict__ bcv) {
    __shared__ unsigned int sbits[NBW];
    for (int i = threadIdx.x; i < NBW; i += blockDim.x) sbits[i] = 0u;
    __syncthreads();
    for (int i = threadIdx.x; i < NSLOT; i += blockDim.x) {
        int r = slot_row(i, users, pos, neg);
        atomicOr(&sbits[r >> 5], 1u << (r & 31));
    }
    __syncthreads();

    int tid = blockIdx.x * blockDim.x + threadIdx.x;
    int nth = gridDim.x * blockDim.x;
    const vint4*   row4 = (const vint4*)adj_row;
    const vint4*   col4 = (const vint4*)adj_col;
    const vfloat4* val4 = (const vfloat4*)adj_val;

    #define PROC(K)                                                            \
    {                                                                          \
        int RR = r[K];                                                         \
        unsigned int w = sbits[RR >> 5];                                       \
        if ((w >> (RR & 31)) & 1u) {                                           \
            int idx = atomicAdd(&cntR[RR], 1);                                 \
            if (idx < CAP) {                                                   \
                long long pv = ((long long)__float_as_int(v[K]) << 32) |       \
                               (unsigned int)c[K];                             \
                __builtin_nontemporal_store(pv, &bcv[(size_t)RR * CAP + idx]); \
            }                                                                  \
        }                                                                      \
    }

    int g = tid;
    if (g >= NQ) return;
    vint4   r = __builtin_nontemporal_load(&row4[g]);
    vint4   c = __builtin_nontemporal_load(&col4[g]);
    vfloat4 v = __builtin_nontemporal_load(&val4[g]);
    for (;;) {
        int gn = g + nth;
        bool more = gn < NQ;
        vint4 rn, cn; vfloat4 vn;
        if (more) {
            rn = __builtin_nontemporal_load(&row4[gn]);
            cn = __builtin_nontemporal_load(&col4[gn]);
            vn = __builtin_nontemporal_load(&val4[gn]);
        }
        PROC(0)
        PROC(1)
        PROC(2)
        PROC(3)
        if (!more) break;
        g = gn; r = rn; c = cn; v = vn;
    }
    #undef PROC
}

// ---------------------------------------------------------------------------
// Kernel 3: one wave per slot; accumulate the row's bucket, write out.
// grp = lane>>4 picks the bucket entry (16 in flight/iter), sub = lane&15
// picks the float4 of the 256 B row. NT bucket loads (read-once), cached
// e0 gathers (reused). shfl_xor(16,32) reduce; grp 0 writes.
// out[slot] = 0.25*e0[r] + 0.75*sum
// ---------------------------------------------------------------------------
__global__ void k_fin(const int* __restrict__ users,
                      const int* __restrict__ pos,
                      const int* __restrict__ neg,
                      const int* __restrict__ cntR,
                      const long long* __restrict__ bcv,
                      const int*   __restrict__ adj_row,
                      const int*   __restrict__ adj_col,
                      const float* __restrict__ adj_val,
                      const float* __restrict__ ue,
                      const float* __restrict__ ie,
                      float* __restrict__ out) {
    int slot = (blockIdx.x * blockDim.x + threadIdx.x) >> 6;
    int lane = threadIdx.x & 63;
    if (slot >= NSLOT) return;
    int r = slot_row(slot, users, pos, neg);
    int n = cntR[r];
    int sub = lane & 15, grp = lane >> 4;
    float4 a = make_float4(0.f, 0.f, 0.f, 0.f);

    if (n <= CAP) {
        const long long* bb = &bcv[(size_t)r * CAP];
        for (int i = 0; i < n; i += 16) {
            int m  = n - 1;
            int e0 = i + grp, e1 = e0 + 4, e2 = e0 + 8, e3 = e0 + 12;
            long long q0 = __builtin_nontemporal_load(&bb[min(e0, m)]);
            long long q1 = __builtin_nontemporal_load(&bb[min(e1, m)]);
            long long q2 = __builtin_nontemporal_load(&bb[min(e2, m)]);
            long long q3 = __builtin_nontemporal_load(&bb[min(e3, m)]);
            float4 x0 = ((const float4*)e0_row((int)(q0 & 0xffffffff), ue, ie))[sub];
            float4 x1 = ((const float4*)e0_row((int)(q1 & 0xffffffff), ue, ie))[sub];
            float4 x2 = ((const float4*)e0_row((int)(q2 & 0xffffffff), ue, ie))[sub];
            float4 x3 = ((const float4*)e0_row((int)(q3 & 0xffffffff), ue, ie))[sub];
            float v0 = (e0 < n) ? __int_as_float((int)(q0 >> 32)) : 0.f;
            float v1 = (e1 < n) ? __int_as_float((int)(q1 >> 32)) : 0.f;
            float v2 = (e2 < n) ? __int_as_float((int)(q2 >> 32)) : 0.f;
            float v3 = (e3 < n) ? __int_as_float((int)(q3 >> 32)) : 0.f;
            a.x += v0 * x0.x; a.y += v0 * x0.y; a.z += v0 * x0.z; a.w += v0 * x0.w;
            a.x += v1 * x1.x; a.y += v1 * x1.y; a.z += v1 * x1.z; a.w += v1 * x1.w;
            a.x += v2 * x2.x; a.y += v2 * x2.y; a.z += v2 * x2.z; a.w += v2 * x2.w;
            a.x += v3 * x3.x; a.y += v3 * x3.y; a.z += v3 * x3.z; a.w += v3 * x3.w;
        }
    } else {
        // statistically impossible (P < 1e-40) bucket overflow: exact rescan
        for (int e = grp; e < NNZ; e += 4) {
            if (adj_row[e] == r) {
                float v = adj_val[e];
                float4 x = ((const float4*)e0_row(adj_col[e], ue, ie))[sub];
                a.x += v * x.x; a.y += v * x.y; a.z += v * x.z; a.w += v * x.w;
            }
        }
    }

    a.x += __shfl_xor(a.x, 16); a.y += __shfl_xor(a.y, 16);
    a.z += __shfl_xor(a.z, 16); a.w += __shfl_xor(a.w, 16);
    a.x += __shfl_xor(a.x, 32); a.y += __shfl_xor(a.y, 32);
    a.z += __shfl_xor(a.z, 32); a.w += __shfl_xor(a.w, 32);

    if (grp == 0) {
        float4 e = ((const float4*)e0_row(r, ue, ie))[sub];
        float4* o = (float4*)&out[(size_t)slot * D];
        o[sub] = make_float4(0.25f * e.x + 0.75f * a.x,
                             0.25f * e.y + 0.75f * a.y,
                             0.25f * e.z + 0.75f * a.z,
                             0.25f * e.w + 0.75f * a.w);
    }
}

// ---------------------------------------------------------------------------
extern "C" void kernel_launch(void* const* d_in, const int* in_sizes, int n_in,
                              void* d_out, int out_size, void* d_ws, size_t ws_size,
                              hipStream_t stream) {
    const int*   users   = (const int*)  d_in[0];
    const int*   pos     = (const int*)  d_in[1];
    const int*   neg     = (const int*)  d_in[2];
    const float* ue      = (const float*)d_in[5];
    const float* ie      = (const float*)d_in[6];
    const int*   adj_row = (const int*)  d_in[7];
    const int*   adj_col = (const int*)  d_in[8];
    const float* adj_val = (const float*)d_in[9];
    float*       out     = (float*)      d_out;

    char* w = (char*)d_ws;
    int*       cntR = (int*)w;       w += (size_t)NTOT * sizeof(int);  /* 600 KB */
    long long* bcv  = (long long*)w;  /* NTOT * CAP * 8 B = 153.6 MB */

    k_mark<<<(NSLOT + 255) / 256, 256, 0, stream>>>(users, pos, neg, cntR);
    k_scan<<<512, 1024, 0, stream>>>(users, pos, neg,
                                     adj_row, adj_col, adj_val, cntR, bcv);
    k_fin <<<(NSLOT * 64 + 255) / 256, 256, 0, stream>>>(users, pos, neg,
                                                         cntR, bcv,
                                                         adj_row, adj_col, adj_val,
                                                         ue, ie, out);
}